// Round 11
// baseline (112.653 us; speedup 1.0000x reference)
//
#include <hip/hip_runtime.h>
#include <math.h>

#define NN 4096
#define KTOP 20
#define EPSF 1e-6f

// ---------------- block sum over 256 threads (4 waves) ----------------
__device__ __forceinline__ float block_rsumf(float v, volatile float* red) {
#pragma unroll
  for (int o = 1; o < 64; o <<= 1) v += __shfl_xor(v, o, 64);
  __syncthreads();
  if ((threadIdx.x & 63) == 0) red[threadIdx.x >> 6] = v;
  __syncthreads();
  return red[0] + red[1] + red[2] + red[3];
}

// ---------------- K0a: partial sums over bt chunks (deterministic) ----------------
__global__ __launch_bounds__(256) void k_prep_a(const float* __restrict__ xh,
    const float* __restrict__ ev, float* __restrict__ psx,
    float* __restrict__ psy, float* __restrict__ pse, int* __restrict__ cnt) {
  if (blockIdx.x == 0 && threadIdx.x == 0) *cnt = 0;
  int ic = blockIdx.x & 15, tc = blockIdx.x >> 4;
  int i = ic * 256 + threadIdx.x;
  const float2* xh2 = (const float2*)xh;
  float sx = 0.f, sy = 0.f, se = 0.f;
  for (int bt = tc * 24; bt < tc * 24 + 24; ++bt) {
    float2 v = xh2[(size_t)bt * NN + i];
    sx += v.x; sy += v.y;
    se += ev[(size_t)bt * NN + i];
  }
  psx[tc * NN + i] = sx; psy[tc * NN + i] = sy; pse[tc * NN + i] = se;
}

// ---------------- K0b: finalize featn / sev / impacted count ----------------
__global__ void k_prep_b(const float* __restrict__ psx, const float* __restrict__ psy,
    const float* __restrict__ pse, float2* __restrict__ featn,
    float* __restrict__ sev, int* __restrict__ cnt) {
  int i = blockIdx.x * 256 + threadIdx.x;
  float sx = 0.f, sy = 0.f, se = 0.f;
#pragma unroll
  for (int t = 0; t < 8; ++t) {
    sx += psx[t * NN + i]; sy += psy[t * NN + i]; se += pse[t * NN + i];
  }
  sx *= (1.f / 192.f); sy *= (1.f / 192.f); se *= (1.f / 192.f);
  float nrm = sqrtf(sx * sx + sy * sy) + EPSF;
  featn[i] = make_float2(sx / nrm, sy / nrm);
  sev[i] = se;
  unsigned long long m = __ballot(se > 0.f);
  if ((threadIdx.x & 63) == 0) atomicAdd(cnt, (int)__popcll(m));
}

// ---- K1: AS & ED per-row chunk partials ONLY (no aexp materialization) ----
// grid dim3(16,128), block 256: 32 rows/block, 8 rows/wave.
__global__ __launch_bounds__(256) void k_as(const float* __restrict__ nv1,
    const float* __restrict__ nv2, const float* __restrict__ base_adj,
    const float* __restrict__ sev, float* __restrict__ aspart,
    float* __restrict__ edpart) {
  const int lane = threadIdx.x & 63, w = threadIdx.x >> 6;
  const int j = blockIdx.x * 256 + lane * 4;
  const int rbase = blockIdx.y * 32;
  const int i0 = rbase + w * 8;

  __shared__ float lps[32][64];
  __shared__ float led[32][64];

  float4 wv[10];
#pragma unroll
  for (int d = 0; d < 10; ++d) wv[d] = *(const float4*)&nv2[d * NN + j];

#pragma unroll
  for (int it = 0; it < 8; ++it) {
    int i = i0 + it;
    const float* r = nv1 + (size_t)i * 10;  // wave-uniform
    float4 a = make_float4(0.f, 0.f, 0.f, 0.f);
#pragma unroll
    for (int d = 0; d < 10; ++d) {
      float rd = r[d];
      a.x += rd * wv[d].x; a.y += rd * wv[d].y;
      a.z += rd * wv[d].z; a.w += rd * wv[d].w;
    }
    float ps = __expf(fmaxf(a.x, 0.f)) + __expf(fmaxf(a.y, 0.f)) +
               __expf(fmaxf(a.z, 0.f)) + __expf(fmaxf(a.w, 0.f));
    float ed = 0.f;
    float esc = sev[i] * 0.6065306597f;  // wave-uniform
    if (esc > 0.f) {                     // uniform branch: ~half the rows
      float4 B = *(const float4*)&base_adj[(size_t)i * NN + j];
      ed = (__expf(fmaxf(esc * B.x, 0.f)) - 1.f) +
           (__expf(fmaxf(esc * B.y, 0.f)) - 1.f) +
           (__expf(fmaxf(esc * B.z, 0.f)) - 1.f) +
           (__expf(fmaxf(esc * B.w, 0.f)) - 1.f);
    }
    lps[w * 8 + it][lane] = ps;
    led[w * 8 + it][lane] = ed;
  }
  __syncthreads();

  // deferred reduce: 8 threads per row, 8 elems each, then 3-step shfl
  const int r = threadIdx.x >> 3, s = threadIdx.x & 7;
  const float4* p0 = (const float4*)&lps[r][s * 8];
  const float4* p1 = (const float4*)&led[r][s * 8];
  float4 x0 = p0[0], x1 = p0[1];
  float4 y0 = p1[0], y1 = p1[1];
  float pa = (x0.x + x0.y) + (x0.z + x0.w) + (x1.x + x1.y) + (x1.z + x1.w);
  float pe = (y0.x + y0.y) + (y0.z + y0.w) + (y1.x + y1.y) + (y1.z + y1.w);
#pragma unroll
  for (int o = 1; o < 8; o <<= 1) {
    pa += __shfl_xor(pa, o, 64);
    pe += __shfl_xor(pe, o, 64);
  }
  if (s == 0) {
    aspart[(rbase + r) * 16 + blockIdx.x] = pa;
    edpart[(rbase + r) * 16 + blockIdx.x] = pe;
  }
}

// ---------------- K1b: per-row fused weights (4 rows/block, 1024 blocks) ----------------
__global__ __launch_bounds__(256) void k_wts(const float2* __restrict__ featn,
    const float* __restrict__ aspart, const float* __restrict__ edpart,
    const float* __restrict__ alpha, const int* __restrict__ cnt,
    float4* __restrict__ wts) {
  const int i0 = blockIdx.x * 4;
  const int tid = threadIdx.x, lane = tid & 63, wv = tid >> 6;
  __shared__ float red[4][4];
  float2 fi0 = featn[i0], fi1 = featn[i0 + 1], fi2 = featn[i0 + 2], fi3 = featn[i0 + 3];
  const float4* f4 = (const float4*)featn;
  float h0 = 0.f, h1 = 0.f, h2 = 0.f, h3 = 0.f;
#pragma unroll
  for (int p = 0; p < 8; ++p) {
    float4 F = f4[p * 256 + tid];
    h0 += __expf(fmaxf(fi0.x * F.x + fi0.y * F.y, 0.f)) +
          __expf(fmaxf(fi0.x * F.z + fi0.y * F.w, 0.f));
    h1 += __expf(fmaxf(fi1.x * F.x + fi1.y * F.y, 0.f)) +
          __expf(fmaxf(fi1.x * F.z + fi1.y * F.w, 0.f));
    h2 += __expf(fmaxf(fi2.x * F.x + fi2.y * F.y, 0.f)) +
          __expf(fmaxf(fi2.x * F.z + fi2.y * F.w, 0.f));
    h3 += __expf(fmaxf(fi3.x * F.x + fi3.y * F.y, 0.f)) +
          __expf(fmaxf(fi3.x * F.z + fi3.y * F.w, 0.f));
  }
#pragma unroll
  for (int o = 1; o < 64; o <<= 1) {
    h0 += __shfl_xor(h0, o, 64); h1 += __shfl_xor(h1, o, 64);
    h2 += __shfl_xor(h2, o, 64); h3 += __shfl_xor(h3, o, 64);
  }
  if (lane == 0) { red[0][wv] = h0; red[1][wv] = h1; red[2][wv] = h2; red[3][wv] = h3; }
  __syncthreads();
  if (tid < 4) {
    int i = i0 + tid;
    float HS = red[tid][0] + red[tid][1] + red[tid][2] + red[tid][3];
    float AS = 0.f, ED = 0.f;
#pragma unroll
    for (int k = 0; k < 16; ++k) {
      AS += aspart[i * 16 + k];
      ED += edpart[i * 16 + k];
    }
    float ES = 4096.f + ED;
    float gamma = 1.f / (1.f + __expf(-alpha[0]));
    float eflag = (*cnt > 0) ? 1.f : 0.f;
    wts[i] = make_float4(0.5f * gamma / HS,
                         0.5f * (1.f - gamma) * eflag / ES,
                         0.5f / AS, 0.f);
  }
}

// ---------------- block-wide exact fallback select (rare; MUST inline) ----------------
__device__ __forceinline__ void fb_row(int i, const float (&v)[16], int* kidx,
    float* kval, float* dinv, volatile float* redf, volatile int* redi,
    int* eq_js, int* eq_cnt, int* slot) {
  const int tid = threadIdx.x;
  const int lane = tid & 63, wv = tid >> 6;
  unsigned cur = 0;
  for (int bit = 30; bit >= 0; --bit) {
    float tf = __uint_as_float(cur | (1u << bit));
    int lc = 0;
#pragma unroll
    for (int c = 0; c < 16; ++c) lc += (v[c] >= tf) ? 1 : 0;
#pragma unroll
    for (int o = 1; o < 64; o <<= 1) lc += __shfl_xor(lc, o, 64);
    __syncthreads();
    if (lane == 0) redi[wv] = lc;
    __syncthreads();
    int tot = redi[0] + redi[1] + redi[2] + redi[3];
    if (tot >= KTOP) cur |= (1u << bit);
  }
  float T = __uint_as_float(cur);
  int lgt = 0;
#pragma unroll
  for (int c = 0; c < 16; ++c) lgt += (v[c] > T) ? 1 : 0;
#pragma unroll
  for (int o = 1; o < 64; o <<= 1) lgt += __shfl_xor(lgt, o, 64);
  __syncthreads();
  if (lane == 0) redi[wv] = lgt;
  if (tid == 0) *eq_cnt = 0;
  __syncthreads();
  int cgt = redi[0] + redi[1] + redi[2] + redi[3];

  float lsum = 0.f;
#pragma unroll
  for (int c = 0; c < 16; ++c) {
    if (v[c] > T) {
      int p = atomicAdd(slot, 1);
      kidx[i * KTOP + p] = tid * 16 + c;
      kval[i * KTOP + p] = v[c];
      lsum += v[c];
    } else if (v[c] == T) {
      int p = atomicAdd(eq_cnt, 1);
      if (p < 64) eq_js[p] = tid * 16 + c;
    }
  }
  __syncthreads();
  int need = KTOP - cgt;
  if (tid == 0) {
    int m = *eq_cnt < 64 ? *eq_cnt : 64;
    for (int s = 0; s < need; ++s) {
      int best = s;
      for (int u = s + 1; u < m; ++u)
        if (eq_js[u] < eq_js[best]) best = u;
      int tmp = eq_js[s]; eq_js[s] = eq_js[best]; eq_js[best] = tmp;
      kidx[i * KTOP + cgt + s] = eq_js[s];
      kval[i * KTOP + cgt + s] = T;
    }
  }
  float tot = block_rsumf(lsum, redf);
  if (tid == 0) dinv[i] = 1.f / sqrtf(tot + (float)need * T + 1.f + EPSF);
}

// ---------------- K2: single-pass v (inline rank-10 logits) + exact top-k ----------------
__global__ __launch_bounds__(256) void k_row(
    const float* __restrict__ base_adj, const float* __restrict__ nv1,
    const float* __restrict__ nv2, const float2* __restrict__ featn,
    const float* __restrict__ sev, const float4* __restrict__ wts,
    int* __restrict__ kidx, float* __restrict__ kval, float* __restrict__ dinv) {
  const int i = blockIdx.x;
  const int tid = threadIdx.x;
  const int lane = tid & 63, wv = tid >> 6;
  const int j0 = tid * 16;

  __shared__ float maxima[256];
  __shared__ float candV[64];
  __shared__ int candJ[64];
  __shared__ float redf[4];
  __shared__ int redi[4];
  __shared__ int eq_js[64];
  __shared__ int ccnt, wslot, eq_cnt;
  __shared__ float sTT;

  float4 w4 = wts[i];
  const float wh = w4.x, we = w4.y, wa = w4.z;
  float2 fi = featn[i];
  float esc = sev[i] * 0.6065306597f;

  const float4* b4 = (const float4*)(base_adj + (size_t)i * NN + j0);
  const float4* f4 = (const float4*)featn;
  const float* v1p = nv1 + (size_t)i * 10;  // block-uniform -> scalar loads

  // ---- a-logits: d-outer accumulation into v[16] ----
  float v[16];
#pragma unroll
  for (int c = 0; c < 16; ++c) v[c] = 0.f;
#pragma unroll
  for (int d = 0; d < 10; ++d) {
    float rd = v1p[d];
    const float4* n4 = (const float4*)(nv2 + (size_t)d * NN + j0);
#pragma unroll
    for (int q = 0; q < 4; ++q) {
      float4 W = n4[q];
      v[4 * q + 0] += rd * W.x; v[4 * q + 1] += rd * W.y;
      v[4 * q + 2] += rd * W.z; v[4 * q + 3] += rd * W.w;
    }
  }

  // ---- fuse all terms, v[] becomes A_dyn values ----
  float m = 0.f;
#pragma unroll
  for (int q = 0; q < 4; ++q) {
    float4 B = b4[q];
    float4 F0 = f4[tid * 8 + 2 * q], F1 = f4[tid * 8 + 2 * q + 1];
    float bq[4] = {B.x, B.y, B.z, B.w};
    float hq[4];
    hq[0] = __expf(fmaxf(fi.x * F0.x + fi.y * F0.y, 0.f));
    hq[1] = __expf(fmaxf(fi.x * F0.z + fi.y * F0.w, 0.f));
    hq[2] = __expf(fmaxf(fi.x * F1.x + fi.y * F1.y, 0.f));
    hq[3] = __expf(fmaxf(fi.x * F1.z + fi.y * F1.w, 0.f));
#pragma unroll
    for (int s = 0; s < 4; ++s) {
      int c = 4 * q + s;
      // base_adj >= 0 always: branchless fused value
      float val = wh * hq[s] + wa * __expf(fmaxf(v[c], 0.f)) + we + 0.5f * bq[s] +
                  we * (__expf(fmaxf(esc * bq[s], 0.f)) - 1.f);
      v[c] = val;
      m = fmaxf(m, val);
    }
  }
  maxima[tid] = m;
  if (tid == 0) { ccnt = 0; wslot = 0; }
  __syncthreads();

  // ---- threshold from 256 thread-maxima (12-bit prefix search, wave 0) ----
  if (wv == 0) {
    float x0 = maxima[lane], x1 = maxima[lane + 64];
    float x2 = maxima[lane + 128], x3 = maxima[lane + 192];
    unsigned cur = 0;
    for (int bit = 30; bit >= 19; --bit) {
      float tf = __uint_as_float(cur | (1u << bit));
      int c_ = __popcll(__ballot(x0 >= tf)) + __popcll(__ballot(x1 >= tf)) +
               __popcll(__ballot(x2 >= tf)) + __popcll(__ballot(x3 >= tf));
      if (c_ >= KTOP) cur |= (1u << bit);
    }
    sTT = __uint_as_float(cur);
  }
  __syncthreads();
  float T0 = sTT;

  // ---- collect candidates (from registers) ----
#pragma unroll
  for (int c = 0; c < 16; ++c) {
    if (v[c] >= T0) {
      int p = atomicAdd(&ccnt, 1);
      if (p < 64) { candV[p] = v[c]; candJ[p] = j0 + c; }
    }
  }
  __syncthreads();
  bool fb = (ccnt > 64);

  // ---- wave-local exact top-20 among candidates ----
  if (!fb && wv == 0) {
    int n = ccnt;
    float lv = (lane < n) ? candV[lane] : 0.f;
    int lj = (lane < n) ? candJ[lane] : 0x7FFFFFFF;
    unsigned cur = 0;
    for (int bit = 30; bit >= 0; --bit) {
      float tf = __uint_as_float(cur | (1u << bit));
      if (__popcll(__ballot(lv >= tf)) >= KTOP) cur |= (1u << bit);
    }
    float T = __uint_as_float(cur);
    bool gt = lv > T;
    int cgt = __popcll(__ballot(gt));
    if (gt) {
      int p = atomicAdd(&wslot, 1);
      kidx[i * KTOP + p] = lj;
      kval[i * KTOP + p] = lv;
    }
    int need = KTOP - cgt;
    bool eq = (lv == T);
    for (int k = 0; k < need; ++k) {
      int pj = eq ? lj : 0x7FFFFFFF;
#pragma unroll
      for (int o = 1; o < 64; o <<= 1) {
        int q = __shfl_xor(pj, o, 64);
        pj = q < pj ? q : pj;
      }
      if (lane == 0) {
        kidx[i * KTOP + cgt + k] = pj;
        kval[i * KTOP + cgt + k] = T;
      }
      if (lj == pj) eq = false;
    }
    float ds = gt ? lv : 0.f;
#pragma unroll
    for (int o = 1; o < 64; o <<= 1) ds += __shfl_xor(ds, o, 64);
    if (lane == 0) dinv[i] = 1.f / sqrtf(ds + (float)need * T + 1.f + EPSF);
  }

  // ---- rare fallback (inlined; v stays in registers) ----
  if (fb) {
    __syncthreads();
    fb_row(i, v, kidx, kval, dinv, redf, redi, eq_js, &eq_cnt, &wslot);
  }
}

// ---------------- K3: write normalized sparse output (LDS row stage) ----------------
__global__ __launch_bounds__(256) void k_write(
    const int* __restrict__ kidx, const float* __restrict__ kval,
    const float* __restrict__ dinv, float* __restrict__ out) {
  const int i = blockIdx.x;
  const int tid = threadIdx.x;
  __shared__ float row[NN];
  float4* r4 = (float4*)row;
#pragma unroll
  for (int c = 0; c < 4; ++c) r4[c * 256 + tid] = make_float4(0.f, 0.f, 0.f, 0.f);
  __syncthreads();
  if (tid < KTOP) {
    int j = kidx[i * KTOP + tid];
    row[j] = kval[i * KTOP + tid];
  }
  __syncthreads();
  float di = dinv[i];
  const float4* dv4 = (const float4*)dinv;
  float4* o4 = (float4*)out;
#pragma unroll
  for (int c = 0; c < 4; ++c) {
    int j4 = c * 256 + tid;
    float4 rv = r4[j4];
    float4 dv = dv4[j4];
    int jb = j4 * 4;
    float4 o;
    o.x = di * (rv.x + ((jb + 0) == i ? 1.f : 0.f)) * dv.x;
    o.y = di * (rv.y + ((jb + 1) == i ? 1.f : 0.f)) * dv.y;
    o.z = di * (rv.z + ((jb + 2) == i ? 1.f : 0.f)) * dv.z;
    o.w = di * (rv.w + ((jb + 3) == i ? 1.f : 0.f)) * dv.w;
    o4[(size_t)i * (NN / 4) + j4] = o;
  }
}

extern "C" void kernel_launch(void* const* d_in, const int* in_sizes, int n_in,
                              void* d_out, int out_size, void* d_ws, size_t ws_size,
                              hipStream_t stream) {
  const float* xh    = (const float*)d_in[0];
  const float* ev    = (const float*)d_in[1];
  const float* base  = (const float*)d_in[2];
  const float* nv1   = (const float*)d_in[3];
  const float* nv2   = (const float*)d_in[4];
  const float* alpha = (const float*)d_in[5];
  float* out = (float*)d_out;

  char* ws = (char*)d_ws;
  int*    cnt    = (int*)ws;                  // 4 B (pad 256)
  float2* featn  = (float2*)(ws + 256);       // 32 KB
  float*  sev    = (float*)(ws + 33024);      // 16 KB
  float*  dinv   = (float*)(ws + 49408);      // 16 KB
  int*    kidx   = (int*)(ws + 65792);        // 320 KB
  float*  kval   = (float*)(ws + 393472);     // 320 KB
  float4* wts    = (float4*)(ws + 721152);    // 64 KB
  float*  psx    = (float*)(ws + 786688);     // 128 KB
  float*  psy    = (float*)(ws + 917760);     // 128 KB
  float*  pse    = (float*)(ws + 1048832);    // 128 KB -> ends 1179904
  // aspart/edpart alias psx..pse (consumed by k_prep_b before k_as writes)
  float*  aspart = (float*)(ws + 786688);     // 256 KB
  float*  edpart = (float*)(ws + 1048832);    // 256 KB -> ends 1310976

  k_prep_a<<<128, 256, 0, stream>>>(xh, ev, psx, psy, pse, cnt);
  k_prep_b<<<16, 256, 0, stream>>>(psx, psy, pse, featn, sev, cnt);
  k_as<<<dim3(16, 128), 256, 0, stream>>>(nv1, nv2, base, sev, aspart, edpart);
  k_wts<<<1024, 256, 0, stream>>>(featn, aspart, edpart, alpha, cnt, wts);
  k_row<<<NN, 256, 0, stream>>>(base, nv1, nv2, featn, sev, wts, kidx, kval, dinv);
  k_write<<<NN, 256, 0, stream>>>(kidx, kval, dinv, out);
}

// Round 14
// 85.949 us; speedup vs baseline: 1.3107x; 1.3107x over previous
//
#include <hip/hip_runtime.h>
#include <math.h>

#define NN 4096
#define KTOP 20
#define EPSF 1e-6f

typedef float nvf4 __attribute__((ext_vector_type(4)));  // native vec for NT store

// ---------------- block sum over 256 threads (4 waves) ----------------
__device__ __forceinline__ float block_rsumf(float v, volatile float* red) {
#pragma unroll
  for (int o = 1; o < 64; o <<= 1) v += __shfl_xor(v, o, 64);
  __syncthreads();
  if ((threadIdx.x & 63) == 0) red[threadIdx.x >> 6] = v;
  __syncthreads();
  return red[0] + red[1] + red[2] + red[3];
}

// ---------------- K0a: partial sums over bt chunks (deterministic) ----------------
__global__ __launch_bounds__(256) void k_prep_a(const float* __restrict__ xh,
    const float* __restrict__ ev, float* __restrict__ psx,
    float* __restrict__ psy, float* __restrict__ pse, int* __restrict__ cnt) {
  if (blockIdx.x == 0 && threadIdx.x == 0) *cnt = 0;
  int ic = blockIdx.x & 15, tc = blockIdx.x >> 4;
  int i = ic * 256 + threadIdx.x;
  const float2* xh2 = (const float2*)xh;
  float sx = 0.f, sy = 0.f, se = 0.f;
  for (int bt = tc * 24; bt < tc * 24 + 24; ++bt) {
    float2 v = xh2[(size_t)bt * NN + i];
    sx += v.x; sy += v.y;
    se += ev[(size_t)bt * NN + i];
  }
  psx[tc * NN + i] = sx; psy[tc * NN + i] = sy; pse[tc * NN + i] = se;
}

// ---------------- K0b: finalize featn / sev / impacted count ----------------
__global__ void k_prep_b(const float* __restrict__ psx, const float* __restrict__ psy,
    const float* __restrict__ pse, float2* __restrict__ featn,
    float* __restrict__ sev, int* __restrict__ cnt) {
  int i = blockIdx.x * 256 + threadIdx.x;
  float sx = 0.f, sy = 0.f, se = 0.f;
#pragma unroll
  for (int t = 0; t < 8; ++t) {
    sx += psx[t * NN + i]; sy += psy[t * NN + i]; se += pse[t * NN + i];
  }
  sx *= (1.f / 192.f); sy *= (1.f / 192.f); se *= (1.f / 192.f);
  float nrm = sqrtf(sx * sx + sy * sy) + EPSF;
  featn[i] = make_float2(sx / nrm, sy / nrm);
  sev[i] = se;
  unsigned long long m = __ballot(se > 0.f);
  if ((threadIdx.x & 63) == 0) atomicAdd(cnt, (int)__popcll(m));
}

// ---- K1: aexp = exp(relu(nv1@nv2)) + per-row AS & ED partials ----
// grid dim3(16,128): XCD-swizzled so the 16 j-blocks of one row-set share an XCD
// (contiguous 16KB write tiles per row within one L2). Nontemporal aexp stores.
__global__ __launch_bounds__(256) void k_gemm(const float* __restrict__ nv1,
    const float* __restrict__ nv2, const float* __restrict__ base_adj,
    const float* __restrict__ sev, float* __restrict__ aexp,
    float* __restrict__ aspart, float* __restrict__ edpart) {
  const int lane = threadIdx.x & 63, w = threadIdx.x >> 6;
  // XCD swizzle: lin%8 = XCD (round-robin dispatch). Give each XCD all 16 bx of
  // a row-set: lin -> (xcd, k); bx = k%16, by = xcd + 8*(k/16). Bijective.
  const int lin = blockIdx.y * 16 + blockIdx.x;
  const int xcd = lin & 7, kk = lin >> 3;
  const int bx = kk & 15, by = xcd + 8 * (kk >> 4);
  const int j = bx * 256 + lane * 4;
  const int rbase = by * 32;
  const int i0 = rbase + w * 8;

  __shared__ float lps[32][64];
  __shared__ float led[32][64];

  float4 wv[10];
#pragma unroll
  for (int d = 0; d < 10; ++d) wv[d] = *(const float4*)&nv2[d * NN + j];

#pragma unroll
  for (int it = 0; it < 8; ++it) {
    int i = i0 + it;
    const float* r = nv1 + (size_t)i * 10;  // wave-uniform
    float4 a = make_float4(0.f, 0.f, 0.f, 0.f);
#pragma unroll
    for (int d = 0; d < 10; ++d) {
      float rd = r[d];
      a.x += rd * wv[d].x; a.y += rd * wv[d].y;
      a.z += rd * wv[d].z; a.w += rd * wv[d].w;
    }
    nvf4 o;
    o.x = __expf(fmaxf(a.x, 0.f)); o.y = __expf(fmaxf(a.y, 0.f));
    o.z = __expf(fmaxf(a.z, 0.f)); o.w = __expf(fmaxf(a.w, 0.f));
    __builtin_nontemporal_store(o, (nvf4*)&aexp[(size_t)i * NN + j]);

    float ed = 0.f;
    float esc = sev[i] * 0.6065306597f;  // wave-uniform
    if (esc > 0.f) {                     // uniform branch: ~half the rows
      float4 B = *(const float4*)&base_adj[(size_t)i * NN + j];
      ed = (__expf(fmaxf(esc * B.x, 0.f)) - 1.f) +
           (__expf(fmaxf(esc * B.y, 0.f)) - 1.f) +
           (__expf(fmaxf(esc * B.z, 0.f)) - 1.f) +
           (__expf(fmaxf(esc * B.w, 0.f)) - 1.f);
    }
    lps[w * 8 + it][lane] = o.x + o.y + o.z + o.w;
    led[w * 8 + it][lane] = ed;
  }
  __syncthreads();

  // deferred reduce: 8 threads per row, 8 elems each, then 3-step shfl
  const int r = threadIdx.x >> 3, s = threadIdx.x & 7;
  const float4* p0 = (const float4*)&lps[r][s * 8];
  const float4* p1 = (const float4*)&led[r][s * 8];
  float4 x0 = p0[0], x1 = p0[1];
  float4 y0 = p1[0], y1 = p1[1];
  float pa = (x0.x + x0.y) + (x0.z + x0.w) + (x1.x + x1.y) + (x1.z + x1.w);
  float pe = (y0.x + y0.y) + (y0.z + y0.w) + (y1.x + y1.y) + (y1.z + y1.w);
#pragma unroll
  for (int o = 1; o < 8; o <<= 1) {
    pa += __shfl_xor(pa, o, 64);
    pe += __shfl_xor(pe, o, 64);
  }
  if (s == 0) {
    aspart[(rbase + r) * 16 + bx] = pa;
    edpart[(rbase + r) * 16 + bx] = pe;
  }
}

// ---------------- K1b: per-row fused weights (4 rows/block, 1024 blocks) ----------------
__global__ __launch_bounds__(256) void k_wts(const float2* __restrict__ featn,
    const float* __restrict__ aspart, const float* __restrict__ edpart,
    const float* __restrict__ alpha, const int* __restrict__ cnt,
    float4* __restrict__ wts) {
  const int i0 = blockIdx.x * 4;
  const int tid = threadIdx.x, lane = tid & 63, wv = tid >> 6;
  __shared__ float red[4][4];
  float2 fi0 = featn[i0], fi1 = featn[i0 + 1], fi2 = featn[i0 + 2], fi3 = featn[i0 + 3];
  const float4* f4 = (const float4*)featn;
  float h0 = 0.f, h1 = 0.f, h2 = 0.f, h3 = 0.f;
#pragma unroll
  for (int p = 0; p < 8; ++p) {
    float4 F = f4[p * 256 + tid];
    h0 += __expf(fmaxf(fi0.x * F.x + fi0.y * F.y, 0.f)) +
          __expf(fmaxf(fi0.x * F.z + fi0.y * F.w, 0.f));
    h1 += __expf(fmaxf(fi1.x * F.x + fi1.y * F.y, 0.f)) +
          __expf(fmaxf(fi1.x * F.z + fi1.y * F.w, 0.f));
    h2 += __expf(fmaxf(fi2.x * F.x + fi2.y * F.y, 0.f)) +
          __expf(fmaxf(fi2.x * F.z + fi2.y * F.w, 0.f));
    h3 += __expf(fmaxf(fi3.x * F.x + fi3.y * F.y, 0.f)) +
          __expf(fmaxf(fi3.x * F.z + fi3.y * F.w, 0.f));
  }
#pragma unroll
  for (int o = 1; o < 64; o <<= 1) {
    h0 += __shfl_xor(h0, o, 64); h1 += __shfl_xor(h1, o, 64);
    h2 += __shfl_xor(h2, o, 64); h3 += __shfl_xor(h3, o, 64);
  }
  if (lane == 0) { red[0][wv] = h0; red[1][wv] = h1; red[2][wv] = h2; red[3][wv] = h3; }
  __syncthreads();
  if (tid < 4) {
    int i = i0 + tid;
    float HS = red[tid][0] + red[tid][1] + red[tid][2] + red[tid][3];
    float AS = 0.f, ED = 0.f;
#pragma unroll
    for (int k = 0; k < 16; ++k) {
      AS += aspart[i * 16 + k];
      ED += edpart[i * 16 + k];
    }
    float ES = 4096.f + ED;
    float gamma = 1.f / (1.f + __expf(-alpha[0]));
    float eflag = (*cnt > 0) ? 1.f : 0.f;
    wts[i] = make_float4(0.5f * gamma / HS,
                         0.5f * (1.f - gamma) * eflag / ES,
                         0.5f / AS, 0.f);
  }
}

// ---------------- block-wide exact fallback select (rare; MUST inline) ----------------
__device__ __forceinline__ void fb_row(int i, const float (&v)[16], int* kidx,
    float* kval, float* dinv, volatile float* redf, volatile int* redi,
    int* eq_js, int* eq_cnt, int* slot) {
  const int tid = threadIdx.x;
  const int lane = tid & 63, wv = tid >> 6;
  unsigned cur = 0;
  for (int bit = 30; bit >= 0; --bit) {
    float tf = __uint_as_float(cur | (1u << bit));
    int lc = 0;
#pragma unroll
    for (int c = 0; c < 16; ++c) lc += (v[c] >= tf) ? 1 : 0;
#pragma unroll
    for (int o = 1; o < 64; o <<= 1) lc += __shfl_xor(lc, o, 64);
    __syncthreads();
    if (lane == 0) redi[wv] = lc;
    __syncthreads();
    int tot = redi[0] + redi[1] + redi[2] + redi[3];
    if (tot >= KTOP) cur |= (1u << bit);
  }
  float T = __uint_as_float(cur);
  int lgt = 0;
#pragma unroll
  for (int c = 0; c < 16; ++c) lgt += (v[c] > T) ? 1 : 0;
#pragma unroll
  for (int o = 1; o < 64; o <<= 1) lgt += __shfl_xor(lgt, o, 64);
  __syncthreads();
  if (lane == 0) redi[wv] = lgt;
  if (tid == 0) *eq_cnt = 0;
  __syncthreads();
  int cgt = redi[0] + redi[1] + redi[2] + redi[3];

  float lsum = 0.f;
#pragma unroll
  for (int c = 0; c < 16; ++c) {
    if (v[c] > T) {
      int p = atomicAdd(slot, 1);
      kidx[i * KTOP + p] = tid * 16 + c;
      kval[i * KTOP + p] = v[c];
      lsum += v[c];
    } else if (v[c] == T) {
      int p = atomicAdd(eq_cnt, 1);
      if (p < 64) eq_js[p] = tid * 16 + c;
    }
  }
  __syncthreads();
  int need = KTOP - cgt;
  if (tid == 0) {
    int m = *eq_cnt < 64 ? *eq_cnt : 64;
    for (int s = 0; s < need; ++s) {
      int best = s;
      for (int u = s + 1; u < m; ++u)
        if (eq_js[u] < eq_js[best]) best = u;
      int tmp = eq_js[s]; eq_js[s] = eq_js[best]; eq_js[best] = tmp;
      kidx[i * KTOP + cgt + s] = eq_js[s];
      kval[i * KTOP + cgt + s] = T;
    }
  }
  float tot = block_rsumf(lsum, redf);
  if (tid == 0) dinv[i] = 1.f / sqrtf(tot + (float)need * T + 1.f + EPSF);
}

// ---------------- K2: single-pass v in registers + exact top-k ----------------
__global__ __launch_bounds__(256) void k_row(
    const float* __restrict__ base_adj, const float* __restrict__ aexp,
    const float2* __restrict__ featn, const float* __restrict__ sev,
    const float4* __restrict__ wts, int* __restrict__ kidx,
    float* __restrict__ kval, float* __restrict__ dinv) {
  const int i = blockIdx.x;
  const int tid = threadIdx.x;
  const int lane = tid & 63, wv = tid >> 6;
  const int j0 = tid * 16;

  __shared__ float maxima[256];
  __shared__ float candV[64];
  __shared__ int candJ[64];
  __shared__ float redf[4];
  __shared__ int redi[4];
  __shared__ int eq_js[64];
  __shared__ int ccnt, wslot, eq_cnt;
  __shared__ float sTT;

  float4 w4 = wts[i];
  const float wh = w4.x, we = w4.y, wa = w4.z;
  float2 fi = featn[i];
  float esc = sev[i] * 0.6065306597f;

  const float4* b4 = (const float4*)(base_adj + (size_t)i * NN + j0);
  const float4* a4 = (const float4*)(aexp + (size_t)i * NN + j0);
  const float4* f4 = (const float4*)featn;

  float v[16];
  float m = 0.f;
#pragma unroll
  for (int q = 0; q < 4; ++q) {
    float4 B = b4[q], A = a4[q];
    float4 F0 = f4[tid * 8 + 2 * q], F1 = f4[tid * 8 + 2 * q + 1];
    float bq[4] = {B.x, B.y, B.z, B.w};
    float aq[4] = {A.x, A.y, A.z, A.w};
    float hq[4];
    hq[0] = __expf(fmaxf(fi.x * F0.x + fi.y * F0.y, 0.f));
    hq[1] = __expf(fmaxf(fi.x * F0.z + fi.y * F0.w, 0.f));
    hq[2] = __expf(fmaxf(fi.x * F1.x + fi.y * F1.y, 0.f));
    hq[3] = __expf(fmaxf(fi.x * F1.z + fi.y * F1.w, 0.f));
#pragma unroll
    for (int s = 0; s < 4; ++s) {
      // base_adj >= 0 always: branchless fused value
      float val = wh * hq[s] + wa * aq[s] + we + 0.5f * bq[s] +
                  we * (__expf(fmaxf(esc * bq[s], 0.f)) - 1.f);
      v[4 * q + s] = val;
      m = fmaxf(m, val);
    }
  }
  maxima[tid] = m;
  if (tid == 0) { ccnt = 0; wslot = 0; }
  __syncthreads();

  // ---- threshold from 256 thread-maxima (12-bit prefix search, wave 0) ----
  if (wv == 0) {
    float x0 = maxima[lane], x1 = maxima[lane + 64];
    float x2 = maxima[lane + 128], x3 = maxima[lane + 192];
    unsigned cur = 0;
    for (int bit = 30; bit >= 19; --bit) {
      float tf = __uint_as_float(cur | (1u << bit));
      int c_ = __popcll(__ballot(x0 >= tf)) + __popcll(__ballot(x1 >= tf)) +
               __popcll(__ballot(x2 >= tf)) + __popcll(__ballot(x3 >= tf));
      if (c_ >= KTOP) cur |= (1u << bit);
    }
    sTT = __uint_as_float(cur);
  }
  __syncthreads();
  float T0 = sTT;

  // ---- collect candidates (from registers) ----
#pragma unroll
  for (int c = 0; c < 16; ++c) {
    if (v[c] >= T0) {
      int p = atomicAdd(&ccnt, 1);
      if (p < 64) { candV[p] = v[c]; candJ[p] = j0 + c; }
    }
  }
  __syncthreads();
  bool fb = (ccnt > 64);

  // ---- wave-local exact top-20 among candidates ----
  if (!fb && wv == 0) {
    int n = ccnt;
    float lv = (lane < n) ? candV[lane] : 0.f;
    int lj = (lane < n) ? candJ[lane] : 0x7FFFFFFF;
    unsigned cur = 0;
    for (int bit = 30; bit >= 0; --bit) {
      float tf = __uint_as_float(cur | (1u << bit));
      if (__popcll(__ballot(lv >= tf)) >= KTOP) cur |= (1u << bit);
    }
    float T = __uint_as_float(cur);
    bool gt = lv > T;
    int cgt = __popcll(__ballot(gt));
    if (gt) {
      int p = atomicAdd(&wslot, 1);
      kidx[i * KTOP + p] = lj;
      kval[i * KTOP + p] = lv;
    }
    int need = KTOP - cgt;
    bool eq = (lv == T);
    for (int k = 0; k < need; ++k) {
      int pj = eq ? lj : 0x7FFFFFFF;
#pragma unroll
      for (int o = 1; o < 64; o <<= 1) {
        int q = __shfl_xor(pj, o, 64);
        pj = q < pj ? q : pj;
      }
      if (lane == 0) {
        kidx[i * KTOP + cgt + k] = pj;
        kval[i * KTOP + cgt + k] = T;
      }
      if (lj == pj) eq = false;
    }
    float ds = gt ? lv : 0.f;
#pragma unroll
    for (int o = 1; o < 64; o <<= 1) ds += __shfl_xor(ds, o, 64);
    if (lane == 0) dinv[i] = 1.f / sqrtf(ds + (float)need * T + 1.f + EPSF);
  }

  // ---- rare fallback (inlined; v stays in registers) ----
  if (fb) {
    __syncthreads();
    fb_row(i, v, kidx, kval, dinv, redf, redi, eq_js, &eq_cnt, &wslot);
  }
}

// ---------------- K3: write normalized sparse output (LDS row stage) ----------------
__global__ __launch_bounds__(256) void k_write(
    const int* __restrict__ kidx, const float* __restrict__ kval,
    const float* __restrict__ dinv, float* __restrict__ out) {
  const int i = blockIdx.x;
  const int tid = threadIdx.x;
  __shared__ float row[NN];
  float4* r4 = (float4*)row;
#pragma unroll
  for (int c = 0; c < 4; ++c) r4[c * 256 + tid] = make_float4(0.f, 0.f, 0.f, 0.f);
  __syncthreads();
  if (tid < KTOP) {
    int j = kidx[i * KTOP + tid];
    row[j] = kval[i * KTOP + tid];
  }
  __syncthreads();
  float di = dinv[i];
  const float4* dv4 = (const float4*)dinv;
  float4* o4 = (float4*)out;
#pragma unroll
  for (int c = 0; c < 4; ++c) {
    int j4 = c * 256 + tid;
    float4 rv = r4[j4];
    float4 dv = dv4[j4];
    int jb = j4 * 4;
    float4 o;
    o.x = di * (rv.x + ((jb + 0) == i ? 1.f : 0.f)) * dv.x;
    o.y = di * (rv.y + ((jb + 1) == i ? 1.f : 0.f)) * dv.y;
    o.z = di * (rv.z + ((jb + 2) == i ? 1.f : 0.f)) * dv.z;
    o.w = di * (rv.w + ((jb + 3) == i ? 1.f : 0.f)) * dv.w;
    o4[(size_t)i * (NN / 4) + j4] = o;
  }
}

extern "C" void kernel_launch(void* const* d_in, const int* in_sizes, int n_in,
                              void* d_out, int out_size, void* d_ws, size_t ws_size,
                              hipStream_t stream) {
  const float* xh    = (const float*)d_in[0];
  const float* ev    = (const float*)d_in[1];
  const float* base  = (const float*)d_in[2];
  const float* nv1   = (const float*)d_in[3];
  const float* nv2   = (const float*)d_in[4];
  const float* alpha = (const float*)d_in[5];
  float* out = (float*)d_out;

  char* ws = (char*)d_ws;
  int*    cnt    = (int*)ws;                  // 4 B (pad 256)
  float2* featn  = (float2*)(ws + 256);       // 32 KB
  float*  sev    = (float*)(ws + 33024);      // 16 KB
  float*  dinv   = (float*)(ws + 49408);      // 16 KB
  int*    kidx   = (int*)(ws + 65792);        // 320 KB
  float*  kval   = (float*)(ws + 393472);     // 320 KB
  float4* wts    = (float4*)(ws + 721152);    // 64 KB
  float*  psx    = (float*)(ws + 786688);     // 128 KB
  float*  psy    = (float*)(ws + 917760);     // 128 KB
  float*  pse    = (float*)(ws + 1048832);    // 128 KB -> ends 1179904
  // aspart/edpart alias psx..pse (consumed by k_prep_b before k_gemm writes)
  float*  aspart = (float*)(ws + 786688);     // 256 KB
  float*  edpart = (float*)(ws + 1048832);    // 256 KB -> ends 1310976

  k_prep_a<<<128, 256, 0, stream>>>(xh, ev, psx, psy, pse, cnt);
  k_prep_b<<<16, 256, 0, stream>>>(psx, psy, pse, featn, sev, cnt);
  // d_out doubles as 64MB f32 aexp scratch until k_write overwrites it
  k_gemm<<<dim3(16, 128), 256, 0, stream>>>(nv1, nv2, base, sev, out, aspart, edpart);
  k_wts<<<1024, 256, 0, stream>>>(featn, aspart, edpart, alpha, cnt, wts);
  k_row<<<NN, 256, 0, stream>>>(base, out, featn, sev, wts, kidx, kval, dinv);
  k_write<<<NN, 256, 0, stream>>>(kidx, kval, dinv, out);
}

// Round 15
// 79.904 us; speedup vs baseline: 1.4098x; 1.0757x over previous
//
#include <hip/hip_runtime.h>
#include <math.h>

#define NN 4096
#define KTOP 20
#define EPSF 1e-6f

// ---------------- block sum over 256 threads (4 waves) ----------------
__device__ __forceinline__ float block_rsumf(float v, volatile float* red) {
#pragma unroll
  for (int o = 1; o < 64; o <<= 1) v += __shfl_xor(v, o, 64);
  __syncthreads();
  if ((threadIdx.x & 63) == 0) red[threadIdx.x >> 6] = v;
  __syncthreads();
  return red[0] + red[1] + red[2] + red[3];
}

// ---------------- K0a: partial sums over bt chunks (deterministic) ----------------
__global__ __launch_bounds__(256) void k_prep_a(const float* __restrict__ xh,
    const float* __restrict__ ev, float* __restrict__ psx,
    float* __restrict__ psy, float* __restrict__ pse, int* __restrict__ cnt) {
  if (blockIdx.x == 0 && threadIdx.x == 0) *cnt = 0;
  int ic = blockIdx.x & 15, tc = blockIdx.x >> 4;
  int i = ic * 256 + threadIdx.x;
  const float2* xh2 = (const float2*)xh;
  float sx = 0.f, sy = 0.f, se = 0.f;
  for (int bt = tc * 24; bt < tc * 24 + 24; ++bt) {
    float2 v = xh2[(size_t)bt * NN + i];
    sx += v.x; sy += v.y;
    se += ev[(size_t)bt * NN + i];
  }
  psx[tc * NN + i] = sx; psy[tc * NN + i] = sy; pse[tc * NN + i] = se;
}

// ---------------- K0b: finalize featn / sev / impacted count ----------------
__global__ void k_prep_b(const float* __restrict__ psx, const float* __restrict__ psy,
    const float* __restrict__ pse, float2* __restrict__ featn,
    float* __restrict__ sev, int* __restrict__ cnt) {
  int i = blockIdx.x * 256 + threadIdx.x;
  float sx = 0.f, sy = 0.f, se = 0.f;
#pragma unroll
  for (int t = 0; t < 8; ++t) {
    sx += psx[t * NN + i]; sy += psy[t * NN + i]; se += pse[t * NN + i];
  }
  sx *= (1.f / 192.f); sy *= (1.f / 192.f); se *= (1.f / 192.f);
  float nrm = sqrtf(sx * sx + sy * sy) + EPSF;
  featn[i] = make_float2(sx / nrm, sy / nrm);
  sev[i] = se;
  unsigned long long m = __ballot(se > 0.f);
  if ((threadIdx.x & 63) == 0) atomicAdd(cnt, (int)__popcll(m));
}

// ---- K1: aexp = exp(relu(nv1@nv2)) + per-row AS & ED partials ----
// grid dim3(4,1024): 4 rows/block, 1024-col window -> each row-iter the block
// writes ONE contiguous 4KB run (page-friendly), walking 4 adjacent rows.
__global__ __launch_bounds__(256) void k_gemm(const float* __restrict__ nv1,
    const float* __restrict__ nv2, const float* __restrict__ base_adj,
    const float* __restrict__ sev, float* __restrict__ aexp,
    float* __restrict__ aspart, float* __restrict__ edpart) {
  const int tid = threadIdx.x, lane = tid & 63;
  const int bx = blockIdx.x;        // 0..3 column window
  const int i0 = blockIdx.y * 4;    // 4 rows
  const int j = bx * 1024 + tid * 4;

  __shared__ float lps[4][256];
  __shared__ float led[4][256];

  float4 wv[10];
#pragma unroll
  for (int d = 0; d < 10; ++d) wv[d] = *(const float4*)&nv2[d * NN + j];

#pragma unroll
  for (int k = 0; k < 4; ++k) {
    int i = i0 + k;
    const float* r = nv1 + (size_t)i * 10;  // block-uniform -> scalar loads
    float4 a = make_float4(0.f, 0.f, 0.f, 0.f);
#pragma unroll
    for (int d = 0; d < 10; ++d) {
      float rd = r[d];
      a.x += rd * wv[d].x; a.y += rd * wv[d].y;
      a.z += rd * wv[d].z; a.w += rd * wv[d].w;
    }
    float4 o;
    o.x = __expf(fmaxf(a.x, 0.f)); o.y = __expf(fmaxf(a.y, 0.f));
    o.z = __expf(fmaxf(a.z, 0.f)); o.w = __expf(fmaxf(a.w, 0.f));
    *(float4*)&aexp[(size_t)i * NN + j] = o;  // 4KB contiguous per block-row

    float ed = 0.f;
    float esc = sev[i] * 0.6065306597f;  // block-uniform
    if (esc > 0.f) {                     // uniform branch: ~half the rows
      float4 B = *(const float4*)&base_adj[(size_t)i * NN + j];
      ed = (__expf(fmaxf(esc * B.x, 0.f)) - 1.f) +
           (__expf(fmaxf(esc * B.y, 0.f)) - 1.f) +
           (__expf(fmaxf(esc * B.z, 0.f)) - 1.f) +
           (__expf(fmaxf(esc * B.w, 0.f)) - 1.f);
    }
    lps[k][tid] = o.x + o.y + o.z + o.w;
    led[k][tid] = ed;
  }
  __syncthreads();

  // deferred reduce: wave w reduces row w (float4 read + 6-step shfl)
  const int w = tid >> 6;
  float4 x = *(const float4*)&lps[w][lane * 4];
  float4 y = *(const float4*)&led[w][lane * 4];
  float pa = (x.x + x.y) + (x.z + x.w);
  float pe = (y.x + y.y) + (y.z + y.w);
#pragma unroll
  for (int o = 1; o < 64; o <<= 1) {
    pa += __shfl_xor(pa, o, 64);
    pe += __shfl_xor(pe, o, 64);
  }
  if (lane == 0) {
    aspart[(i0 + w) * 4 + bx] = pa;
    edpart[(i0 + w) * 4 + bx] = pe;
  }
}

// ---------------- K1b: per-row fused weights (4 rows/block, 1024 blocks) ----------------
__global__ __launch_bounds__(256) void k_wts(const float2* __restrict__ featn,
    const float* __restrict__ aspart, const float* __restrict__ edpart,
    const float* __restrict__ alpha, const int* __restrict__ cnt,
    float4* __restrict__ wts) {
  const int i0 = blockIdx.x * 4;
  const int tid = threadIdx.x, lane = tid & 63, wv = tid >> 6;
  __shared__ float red[4][4];
  float2 fi0 = featn[i0], fi1 = featn[i0 + 1], fi2 = featn[i0 + 2], fi3 = featn[i0 + 3];
  const float4* f4 = (const float4*)featn;
  float h0 = 0.f, h1 = 0.f, h2 = 0.f, h3 = 0.f;
#pragma unroll
  for (int p = 0; p < 8; ++p) {
    float4 F = f4[p * 256 + tid];
    h0 += __expf(fmaxf(fi0.x * F.x + fi0.y * F.y, 0.f)) +
          __expf(fmaxf(fi0.x * F.z + fi0.y * F.w, 0.f));
    h1 += __expf(fmaxf(fi1.x * F.x + fi1.y * F.y, 0.f)) +
          __expf(fmaxf(fi1.x * F.z + fi1.y * F.w, 0.f));
    h2 += __expf(fmaxf(fi2.x * F.x + fi2.y * F.y, 0.f)) +
          __expf(fmaxf(fi2.x * F.z + fi2.y * F.w, 0.f));
    h3 += __expf(fmaxf(fi3.x * F.x + fi3.y * F.y, 0.f)) +
          __expf(fmaxf(fi3.x * F.z + fi3.y * F.w, 0.f));
  }
#pragma unroll
  for (int o = 1; o < 64; o <<= 1) {
    h0 += __shfl_xor(h0, o, 64); h1 += __shfl_xor(h1, o, 64);
    h2 += __shfl_xor(h2, o, 64); h3 += __shfl_xor(h3, o, 64);
  }
  if (lane == 0) { red[0][wv] = h0; red[1][wv] = h1; red[2][wv] = h2; red[3][wv] = h3; }
  __syncthreads();
  if (tid < 4) {
    int i = i0 + tid;
    float HS = red[tid][0] + red[tid][1] + red[tid][2] + red[tid][3];
    float AS = 0.f, ED = 0.f;
#pragma unroll
    for (int k = 0; k < 4; ++k) {
      AS += aspart[i * 4 + k];
      ED += edpart[i * 4 + k];
    }
    float ES = 4096.f + ED;
    float gamma = 1.f / (1.f + __expf(-alpha[0]));
    float eflag = (*cnt > 0) ? 1.f : 0.f;
    wts[i] = make_float4(0.5f * gamma / HS,
                         0.5f * (1.f - gamma) * eflag / ES,
                         0.5f / AS, 0.f);
  }
}

// ---------------- block-wide exact fallback select (rare; MUST inline) ----------------
__device__ __forceinline__ void fb_row(int i, const float (&v)[16], int* kidx,
    float* kval, float* dinv, volatile float* redf, volatile int* redi,
    int* eq_js, int* eq_cnt, int* slot) {
  const int tid = threadIdx.x;
  const int lane = tid & 63, wv = tid >> 6;
  unsigned cur = 0;
  for (int bit = 30; bit >= 0; --bit) {
    float tf = __uint_as_float(cur | (1u << bit));
    int lc = 0;
#pragma unroll
    for (int c = 0; c < 16; ++c) lc += (v[c] >= tf) ? 1 : 0;
#pragma unroll
    for (int o = 1; o < 64; o <<= 1) lc += __shfl_xor(lc, o, 64);
    __syncthreads();
    if (lane == 0) redi[wv] = lc;
    __syncthreads();
    int tot = redi[0] + redi[1] + redi[2] + redi[3];
    if (tot >= KTOP) cur |= (1u << bit);
  }
  float T = __uint_as_float(cur);
  int lgt = 0;
#pragma unroll
  for (int c = 0; c < 16; ++c) lgt += (v[c] > T) ? 1 : 0;
#pragma unroll
  for (int o = 1; o < 64; o <<= 1) lgt += __shfl_xor(lgt, o, 64);
  __syncthreads();
  if (lane == 0) redi[wv] = lgt;
  if (tid == 0) *eq_cnt = 0;
  __syncthreads();
  int cgt = redi[0] + redi[1] + redi[2] + redi[3];

  float lsum = 0.f;
#pragma unroll
  for (int c = 0; c < 16; ++c) {
    if (v[c] > T) {
      int p = atomicAdd(slot, 1);
      kidx[i * KTOP + p] = tid * 16 + c;
      kval[i * KTOP + p] = v[c];
      lsum += v[c];
    } else if (v[c] == T) {
      int p = atomicAdd(eq_cnt, 1);
      if (p < 64) eq_js[p] = tid * 16 + c;
    }
  }
  __syncthreads();
  int need = KTOP - cgt;
  if (tid == 0) {
    int m = *eq_cnt < 64 ? *eq_cnt : 64;
    for (int s = 0; s < need; ++s) {
      int best = s;
      for (int u = s + 1; u < m; ++u)
        if (eq_js[u] < eq_js[best]) best = u;
      int tmp = eq_js[s]; eq_js[s] = eq_js[best]; eq_js[best] = tmp;
      kidx[i * KTOP + cgt + s] = eq_js[s];
      kval[i * KTOP + cgt + s] = T;
    }
  }
  float tot = block_rsumf(lsum, redf);
  if (tid == 0) dinv[i] = 1.f / sqrtf(tot + (float)need * T + 1.f + EPSF);
}

// ---------------- K2: single-pass v in registers + exact top-k ----------------
__global__ __launch_bounds__(256) void k_row(
    const float* __restrict__ base_adj, const float* __restrict__ aexp,
    const float2* __restrict__ featn, const float* __restrict__ sev,
    const float4* __restrict__ wts, int* __restrict__ kidx,
    float* __restrict__ kval, float* __restrict__ dinv) {
  const int i = blockIdx.x;
  const int tid = threadIdx.x;
  const int lane = tid & 63, wv = tid >> 6;
  const int j0 = tid * 16;

  __shared__ float maxima[256];
  __shared__ float candV[64];
  __shared__ int candJ[64];
  __shared__ float redf[4];
  __shared__ int redi[4];
  __shared__ int eq_js[64];
  __shared__ int ccnt, wslot, eq_cnt;
  __shared__ float sTT;

  float4 w4 = wts[i];
  const float wh = w4.x, we = w4.y, wa = w4.z;
  float2 fi = featn[i];
  float esc = sev[i] * 0.6065306597f;

  const float4* b4 = (const float4*)(base_adj + (size_t)i * NN + j0);
  const float4* a4 = (const float4*)(aexp + (size_t)i * NN + j0);
  const float4* f4 = (const float4*)featn;

  float v[16];
  float m = 0.f;
#pragma unroll
  for (int q = 0; q < 4; ++q) {
    float4 B = b4[q], A = a4[q];
    float4 F0 = f4[tid * 8 + 2 * q], F1 = f4[tid * 8 + 2 * q + 1];
    float bq[4] = {B.x, B.y, B.z, B.w};
    float aq[4] = {A.x, A.y, A.z, A.w};
    float hq[4];
    hq[0] = __expf(fmaxf(fi.x * F0.x + fi.y * F0.y, 0.f));
    hq[1] = __expf(fmaxf(fi.x * F0.z + fi.y * F0.w, 0.f));
    hq[2] = __expf(fmaxf(fi.x * F1.x + fi.y * F1.y, 0.f));
    hq[3] = __expf(fmaxf(fi.x * F1.z + fi.y * F1.w, 0.f));
#pragma unroll
    for (int s = 0; s < 4; ++s) {
      // base_adj >= 0 always: branchless fused value
      float val = wh * hq[s] + wa * aq[s] + we + 0.5f * bq[s] +
                  we * (__expf(fmaxf(esc * bq[s], 0.f)) - 1.f);
      v[4 * q + s] = val;
      m = fmaxf(m, val);
    }
  }
  maxima[tid] = m;
  if (tid == 0) { ccnt = 0; wslot = 0; }
  __syncthreads();

  // ---- threshold from 256 thread-maxima (12-bit prefix search, wave 0) ----
  if (wv == 0) {
    float x0 = maxima[lane], x1 = maxima[lane + 64];
    float x2 = maxima[lane + 128], x3 = maxima[lane + 192];
    unsigned cur = 0;
    for (int bit = 30; bit >= 19; --bit) {
      float tf = __uint_as_float(cur | (1u << bit));
      int c_ = __popcll(__ballot(x0 >= tf)) + __popcll(__ballot(x1 >= tf)) +
               __popcll(__ballot(x2 >= tf)) + __popcll(__ballot(x3 >= tf));
      if (c_ >= KTOP) cur |= (1u << bit);
    }
    sTT = __uint_as_float(cur);
  }
  __syncthreads();
  float T0 = sTT;

  // ---- collect candidates (from registers) ----
#pragma unroll
  for (int c = 0; c < 16; ++c) {
    if (v[c] >= T0) {
      int p = atomicAdd(&ccnt, 1);
      if (p < 64) { candV[p] = v[c]; candJ[p] = j0 + c; }
    }
  }
  __syncthreads();
  bool fb = (ccnt > 64);

  // ---- wave-local exact top-20 among candidates ----
  if (!fb && wv == 0) {
    int n = ccnt;
    float lv = (lane < n) ? candV[lane] : 0.f;
    int lj = (lane < n) ? candJ[lane] : 0x7FFFFFFF;
    unsigned cur = 0;
    for (int bit = 30; bit >= 0; --bit) {
      float tf = __uint_as_float(cur | (1u << bit));
      if (__popcll(__ballot(lv >= tf)) >= KTOP) cur |= (1u << bit);
    }
    float T = __uint_as_float(cur);
    bool gt = lv > T;
    int cgt = __popcll(__ballot(gt));
    if (gt) {
      int p = atomicAdd(&wslot, 1);
      kidx[i * KTOP + p] = lj;
      kval[i * KTOP + p] = lv;
    }
    int need = KTOP - cgt;
    bool eq = (lv == T);
    for (int k = 0; k < need; ++k) {
      int pj = eq ? lj : 0x7FFFFFFF;
#pragma unroll
      for (int o = 1; o < 64; o <<= 1) {
        int q = __shfl_xor(pj, o, 64);
        pj = q < pj ? q : pj;
      }
      if (lane == 0) {
        kidx[i * KTOP + cgt + k] = pj;
        kval[i * KTOP + cgt + k] = T;
      }
      if (lj == pj) eq = false;
    }
    float ds = gt ? lv : 0.f;
#pragma unroll
    for (int o = 1; o < 64; o <<= 1) ds += __shfl_xor(ds, o, 64);
    if (lane == 0) dinv[i] = 1.f / sqrtf(ds + (float)need * T + 1.f + EPSF);
  }

  // ---- rare fallback (inlined; v stays in registers) ----
  if (fb) {
    __syncthreads();
    fb_row(i, v, kidx, kval, dinv, redf, redi, eq_js, &eq_cnt, &wslot);
  }
}

// ---------------- K3: write normalized sparse output (LDS row stage) ----------------
__global__ __launch_bounds__(256) void k_write(
    const int* __restrict__ kidx, const float* __restrict__ kval,
    const float* __restrict__ dinv, float* __restrict__ out) {
  const int i = blockIdx.x;
  const int tid = threadIdx.x;
  __shared__ float row[NN];
  float4* r4 = (float4*)row;
#pragma unroll
  for (int c = 0; c < 4; ++c) r4[c * 256 + tid] = make_float4(0.f, 0.f, 0.f, 0.f);
  __syncthreads();
  if (tid < KTOP) {
    int j = kidx[i * KTOP + tid];
    row[j] = kval[i * KTOP + tid];
  }
  __syncthreads();
  float di = dinv[i];
  const float4* dv4 = (const float4*)dinv;
  float4* o4 = (float4*)out;
#pragma unroll
  for (int c = 0; c < 4; ++c) {
    int j4 = c * 256 + tid;
    float4 rv = r4[j4];
    float4 dv = dv4[j4];
    int jb = j4 * 4;
    float4 o;
    o.x = di * (rv.x + ((jb + 0) == i ? 1.f : 0.f)) * dv.x;
    o.y = di * (rv.y + ((jb + 1) == i ? 1.f : 0.f)) * dv.y;
    o.z = di * (rv.z + ((jb + 2) == i ? 1.f : 0.f)) * dv.z;
    o.w = di * (rv.w + ((jb + 3) == i ? 1.f : 0.f)) * dv.w;
    o4[(size_t)i * (NN / 4) + j4] = o;
  }
}

extern "C" void kernel_launch(void* const* d_in, const int* in_sizes, int n_in,
                              void* d_out, int out_size, void* d_ws, size_t ws_size,
                              hipStream_t stream) {
  const float* xh    = (const float*)d_in[0];
  const float* ev    = (const float*)d_in[1];
  const float* base  = (const float*)d_in[2];
  const float* nv1   = (const float*)d_in[3];
  const float* nv2   = (const float*)d_in[4];
  const float* alpha = (const float*)d_in[5];
  float* out = (float*)d_out;

  char* ws = (char*)d_ws;
  int*    cnt    = (int*)ws;                  // 4 B (pad 256)
  float2* featn  = (float2*)(ws + 256);       // 32 KB
  float*  sev    = (float*)(ws + 33024);      // 16 KB
  float*  dinv   = (float*)(ws + 49408);      // 16 KB
  int*    kidx   = (int*)(ws + 65792);        // 320 KB
  float*  kval   = (float*)(ws + 393472);     // 320 KB
  float4* wts    = (float4*)(ws + 721152);    // 64 KB
  float*  psx    = (float*)(ws + 786688);     // 128 KB
  float*  psy    = (float*)(ws + 917760);     // 128 KB
  float*  pse    = (float*)(ws + 1048832);    // 128 KB -> ends 1179904
  // aspart/edpart alias psx/psy region (consumed by k_prep_b before k_gemm writes)
  float*  aspart = (float*)(ws + 786688);     // 64 KB
  float*  edpart = (float*)(ws + 917760);     // 64 KB

  k_prep_a<<<128, 256, 0, stream>>>(xh, ev, psx, psy, pse, cnt);
  k_prep_b<<<16, 256, 0, stream>>>(psx, psy, pse, featn, sev, cnt);
  // d_out doubles as 64MB f32 aexp scratch until k_write overwrites it
  k_gemm<<<dim3(4, 1024), 256, 0, stream>>>(nv1, nv2, base, sev, out, aspart, edpart);
  k_wts<<<1024, 256, 0, stream>>>(featn, aspart, edpart, alpha, cnt, wts);
  k_row<<<NN, 256, 0, stream>>>(base, out, featn, sev, wts, kidx, kval, dinv);
  k_write<<<NN, 256, 0, stream>>>(kidx, kval, dinv, out);
}